// Round 5
// baseline (82.653 us; speedup 1.0000x reference)
//
#include <hip/hip_runtime.h>
#include <climits>
#include <float.h>

#define H_     512
#define W_     512
#define C_     80
#define HW_    (H_ * W_)           // 262144
#define NTOT   (C_ * HW_)          // 20,971,520
#define K_     10
#define R_     16                  // rows per strip
#define NSTRIP (C_ * (H_ / R_) * (W_ / 4))   // 80*32*128 = 327680
#define NBLK   (NSTRIP / 256)                // 1280
#define NWAVE  (NBLK * 4)                    // 5120 waves
#define WCAP   16                            // candidate slots per wave
#define TAU    0.9999f

__device__ __forceinline__ float max3f(float a, float b, float c) {
    return fmaxf(fmaxf(a, b), c);
}

// Fully-unrolled bubble insert into descending (tv, ti); tie -> lower index.
__device__ __forceinline__ void insert10(float (&tv)[K_], int (&ti)[K_],
                                         float s, int ridx) {
#pragma unroll
    for (int j = 0; j < K_; ++j) {
        const bool better = (s > tv[j]) || (s == tv[j] && ridx < ti[j]);
        const float ov = tv[j]; const int oi = ti[j];
        if (better) { tv[j] = s; ti[j] = ridx; s = ov; ridx = oi; }
    }
}

// ---------------------------------------------------------------------------
// k_scan: per-thread 16-row strip. Hot loop: 1 float4 load + 3 fmax + 1 cmp
// + ballot per row (center row only — raw > TAU is necessary for a keep).
// Flagged rows re-evaluated in a wave-uniform rare pass; candidates compacted
// via ballot/mbcnt into a private per-wave region. No global atomics, no
// pre-initialized state.
// ---------------------------------------------------------------------------
__global__ __launch_bounds__(256) void k_scan(const float* __restrict__ kp,
                                              int*  __restrict__ wcnt,
                                              int2* __restrict__ wpair)
{
    const int s    = blockIdx.x * 256 + threadIdx.x;  // strip id
    const int lane = threadIdx.x & 63;
    const int wid  = (blockIdx.x << 2) | (threadIdx.x >> 6);
    const int cls  = s >> 12;                         // 4096 strips per plane
    const int r    = s & 4095;
    const int g    = r >> 7;                          // rowgroup (32 per plane)
    const int xc   = r & 127;                         // x-chunk
    const int y0   = g << 4;
    const int x    = xc << 2;

    const float* plane = kp + (cls << 18);
    const float* p     = plane + (y0 << 9) + x;

    // ---- hot loop: flag rows where any wave lane has a value > TAU ---------
    unsigned whot = 0;
#pragma unroll
    for (int i = 0; i < R_; ++i) {
        const float4 rc = *(const float4*)(p + (i << 9));
        const float m4 = fmaxf(fmaxf(rc.x, rc.y), fmaxf(rc.z, rc.w));
        const unsigned long long bl = __ballot(m4 > TAU);
        whot |= (bl != 0ull ? 1u : 0u) << i;
    }

    // ---- rare pass: full 3x3 evaluation on flagged rows (wave-uniform) -----
    unsigned wcount = 0;
    while (whot) {
        const int i = __ffs(whot) - 1;
        whot &= whot - 1;

        const int y   = y0 + i;
        const int ym1 = (y > 0)      ? y - 1 : 0;
        const int yp1 = (y < H_ - 1) ? y + 1 : H_ - 1;
        const float4 ru = *(const float4*)(plane + (ym1 << 9) + x);
        const float4 rc = *(const float4*)(plane + (y   << 9) + x);
        const float4 rd = *(const float4*)(plane + (yp1 << 9) + x);
        const int xl = (x > 0)      ? x - 1 : 0;
        const int xr = (x + 4 < W_) ? x + 4 : W_ - 1;
        const float la = plane[(ym1 << 9) + xl];
        const float lb = plane[(y   << 9) + xl];
        const float lc = plane[(yp1 << 9) + xl];
        const float ka = plane[(ym1 << 9) + xr];
        const float kb = plane[(y   << 9) + xr];
        const float kc = plane[(yp1 << 9) + xr];

        const float vm0 = max3f(ru.x, rc.x, rd.x);
        const float vm1 = max3f(ru.y, rc.y, rd.y);
        const float vm2 = max3f(ru.z, rc.z, rd.z);
        const float vm3 = max3f(ru.w, rc.w, rd.w);
        const float lv  = (x > 0)      ? max3f(la, lb, lc) : -FLT_MAX;
        const float rv  = (x + 4 < W_) ? max3f(ka, kb, kc) : -FLT_MAX;

        const float w0 = fmaxf(lv, fmaxf(vm0, vm1));
        const float w1 = max3f(vm0, vm1, vm2);
        const float w2 = max3f(vm1, vm2, vm3);
        const float w3 = fmaxf(fmaxf(vm2, vm3), rv);

        const int base = ((y << 9) + x) * C_ + cls;   // reference flat index

        const float vals[4] = { rc.x, rc.y, rc.z, rc.w };
        const float wins[4] = { w0, w1, w2, w3 };
#pragma unroll
        for (int c2 = 0; c2 < 4; ++c2) {
            const float v = vals[c2];
            const bool take = (v > TAU) && (v == wins[c2]);
            const unsigned long long mk = __ballot(take);
            if (mk) {
                const int rank = __builtin_amdgcn_mbcnt_hi(
                    (unsigned)(mk >> 32),
                    __builtin_amdgcn_mbcnt_lo((unsigned)mk, 0));
                if (take) {
                    const unsigned slot = wcount + (unsigned)rank;
                    if (slot < WCAP)
                        wpair[wid * WCAP + slot] =
                            make_int2(__float_as_int(v), base + c2 * C_);
                }
                wcount += (unsigned)__popcll(mk);  // uniform across wave
            }
        }
    }

    if (lane == 0) wcnt[wid] = (int)wcount;   // written fresh every call
}

// ---------------------------------------------------------------------------
// k_reduce: single block. If every wave count <= WCAP and total >= 10, the
// candidate set provably contains the global top-10 (all candidates > TAU >=
// every non-candidate score). Otherwise exhaustive fallback. Then decode.
// ---------------------------------------------------------------------------
__global__ __launch_bounds__(256) void k_reduce(const int*  __restrict__ wcnt,
                                                const int2* __restrict__ wpair,
                                                const float* __restrict__ kp,
                                                const float* __restrict__ off,
                                                const float* __restrict__ sz,
                                                float* __restrict__ out)
{
    const int t = threadIdx.x;
    float tv[K_];
    int   ti[K_];
#pragma unroll
    for (int k = 0; k < K_; ++k) { tv[k] = 0.0f; ti[k] = INT_MAX; }

    int myn = 0, myok = 1;
    for (int w = t; w < NWAVE; w += 256) {
        int c = wcnt[w];
        if (c < 0 || c > WCAP) { myok = 0; c = 0; }
        myn += c;
        for (int j = 0; j < c; ++j) {
            const int2 e = wpair[w * WCAP + j];
            insert10(tv, ti, __int_as_float(e.x), e.y);
        }
    }

    __shared__ int sn[256], sk[256];
    sn[t] = myn; sk[t] = myok;
    __syncthreads();
    for (int st = 128; st > 0; st >>= 1) {
        if (t < st) { sn[t] += sn[t + st]; sk[t] &= sk[t + st]; }
        __syncthreads();
    }
    const bool valid = (sk[0] != 0) && (sn[0] >= K_);
    __syncthreads();

    if (!valid) {
        // exhaustive fallback (never taken for the benchmark input)
#pragma unroll
        for (int k = 0; k < K_; ++k) { tv[k] = 0.0f; ti[k] = INT_MAX; }
        float thresh = 0.0f;
        for (int idx = t; idx < NTOT; idx += 256) {
            const int cls = idx >> 18;
            const int sp  = idx & (HW_ - 1);
            const int y   = sp >> 9;
            const int x   = sp & (W_ - 1);
            const float* plane = kp + (cls << 18);
            const float v = plane[sp];
            float wmax = v;
            const int yA = (y > 0)      ? y - 1 : 0;
            const int yB = (y < H_ - 1) ? y + 1 : H_ - 1;
            const int xA = (x > 0)      ? x - 1 : 0;
            const int xB = (x < W_ - 1) ? x + 1 : W_ - 1;
            for (int yy = yA; yy <= yB; ++yy)
                for (int xx = xA; xx <= xB; ++xx)
                    wmax = fmaxf(wmax, plane[(yy << 9) + xx]);
            if (v == wmax && v > thresh) {
                insert10(tv, ti, v, sp * C_ + cls);
                thresh = tv[K_ - 1];
            }
        }
    }

    // ---- block merge of sorted 10-lists ------------------------------------
    __shared__ float sv[256][K_];
    __shared__ int   si[256][K_];
#pragma unroll
    for (int k = 0; k < K_; ++k) { sv[t][k] = tv[k]; si[t][k] = ti[k]; }
    __syncthreads();

    for (int stride = 128; stride > 0; stride >>= 1) {
        if (t < stride) {
            float mv[K_]; int mi[K_];
            int a = 0, b = 0;
#pragma unroll
            for (int k = 0; k < K_; ++k) {
                const float va = sv[t][a], vb = sv[t + stride][b];
                const int   ia = si[t][a], ib = si[t + stride][b];
                const bool takeA = (va > vb) || (va == vb && ia <= ib);
                if (takeA) { mv[k] = va; mi[k] = ia; ++a; }
                else       { mv[k] = vb; mi[k] = ib; ++b; }
            }
#pragma unroll
            for (int k = 0; k < K_; ++k) { sv[t][k] = mv[k]; si[t][k] = mi[k]; }
        }
        __syncthreads();
    }

    if (t < K_) {
        const float score = sv[0][t];
        const int   index = si[0][t];
        const int   chan  = index / C_;          // y*W + x
        const int   cls   = index - chan * C_;
        const int   y     = chan >> 9;
        const int   x     = chan & (W_ - 1);

        // last-dim flip: y-component <- channel 1, x-component <- channel 0
        const float offy = off[HW_ + chan];
        const float offx = off[chan];
        const float szy  = sz[HW_ + chan];
        const float szx  = sz[chan];

        const float py = (float)y + offy;
        const float px = (float)x + offx;
        const float hy = 0.5f * szy;
        const float hx = 0.5f * szx;

        const float lo = 0.0f, hi = (float)(W_ - 1);
        out[t * 4 + 0] = fminf(fmaxf(py - hy, lo), hi) * 4.0f;
        out[t * 4 + 1] = fminf(fmaxf(px - hx, lo), hi) * 4.0f;
        out[t * 4 + 2] = fminf(fmaxf(py + hy, lo), hi) * 4.0f;
        out[t * 4 + 3] = fminf(fmaxf(px + hx, lo), hi) * 4.0f;
        out[40 + t]    = (float)cls;   // detection_classes
        out[50 + t]    = score;        // detection_scores
    }
}

// ---------------------------------------------------------------------------
extern "C" void kernel_launch(void* const* d_in, const int* in_sizes, int n_in,
                              void* d_out, int out_size, void* d_ws, size_t ws_size,
                              hipStream_t stream)
{
    const float* off = (const float*)d_in[0];   // [1,2,512,512]
    const float* sz  = (const float*)d_in[1];   // [1,2,512,512]
    const float* kp  = (const float*)d_in[2];   // [1,80,512,512]
    float* out = (float*)d_out;                 // 40 + 10 + 10 = 60 floats

    // ws layout: wcnt[NWAVE] ints | wpair[NWAVE*WCAP] int2
    int*  wcnt  = (int*)d_ws;
    int2* wpair = (int2*)((char*)d_ws + (size_t)NWAVE * sizeof(int));

    k_scan<<<NBLK, 256, 0, stream>>>(kp, wcnt, wpair);
    k_reduce<<<1, 256, 0, stream>>>(wcnt, wpair, kp, off, sz, out);
}

// Round 6
// 55.176 us; speedup vs baseline: 1.4980x; 1.4980x over previous
//
#include <hip/hip_runtime.h>
#include <climits>
#include <float.h>

#define H_     512
#define W_     512
#define C_     80
#define HW_    (H_ * W_)           // 262144
#define NTOT   (C_ * HW_)          // 20,971,520
#define K_     10
#define R_     16                  // rows per strip
#define NSTRIP (C_ * (H_ / R_) * (W_ / 4))   // 80*32*128 = 327680
#define NBLK   (NSTRIP / 256)                // 1280
#define BPT    (NBLK / 256)                  // 5 blocks per reduce thread
#define BSLOTS 8                             // per-block candidate slots (64 B)
#define TAU    0.9999f

__device__ __forceinline__ float max3f(float a, float b, float c) {
    return fmaxf(fmaxf(a, b), c);
}

// Fully-unrolled bubble insert into descending (tv, ti); tie -> lower index.
__device__ __forceinline__ void insert10(float (&tv)[K_], int (&ti)[K_],
                                         float s, int ridx) {
#pragma unroll
    for (int j = 0; j < K_; ++j) {
        const bool better = (s > tv[j]) || (s == tv[j] && ridx < ti[j]);
        const float ov = tv[j]; const int oi = ti[j];
        if (better) { tv[j] = s; ti[j] = ridx; s = ov; ridx = oi; }
    }
}

// ---------------------------------------------------------------------------
// k_scan: per-thread 16-row strip. Hot loop: 1 float4 load + 3 fmax + 1 cmp
// + ballot per row. Flagged rows re-evaluated in a rare wave-uniform pass;
// candidates go to an LDS block counter + slots, written out as ONE 64-byte
// line per block plus a 1-byte count. No global atomics, no init dispatch.
// ---------------------------------------------------------------------------
__global__ __launch_bounds__(256) void k_scan(const float* __restrict__ kp,
                                              unsigned char* __restrict__ gbcnt,
                                              int2* __restrict__ gbpair)
{
    __shared__ int  bcnt_s;
    __shared__ int2 bslots[BSLOTS];
    if (threadIdx.x == 0) bcnt_s = 0;
    __syncthreads();

    const int s   = blockIdx.x * 256 + threadIdx.x;   // strip id
    const int cls = s >> 12;                          // 4096 strips per plane
    const int r   = s & 4095;
    const int g   = r >> 7;                           // rowgroup (32 per plane)
    const int xc  = r & 127;                          // x-chunk
    const int y0  = g << 4;
    const int x   = xc << 2;

    const float* plane = kp + (cls << 18);
    const float* p     = plane + (y0 << 9) + x;

    // ---- hot loop: flag rows where any wave lane has a center value > TAU --
    unsigned whot = 0;
#pragma unroll
    for (int i = 0; i < R_; ++i) {
        const float4 rc = *(const float4*)(p + (i << 9));
        const float m4 = fmaxf(fmaxf(rc.x, rc.y), fmaxf(rc.z, rc.w));
        const unsigned long long bl = __ballot(m4 > TAU);
        whot |= (bl != 0ull ? 1u : 0u) << i;
    }

    // ---- rare pass: full 3x3 evaluation on flagged rows --------------------
    while (whot) {
        const int i = __ffs(whot) - 1;
        whot &= whot - 1;

        const int y   = y0 + i;
        const int ym1 = (y > 0)      ? y - 1 : 0;
        const int yp1 = (y < H_ - 1) ? y + 1 : H_ - 1;
        const float4 ru = *(const float4*)(plane + (ym1 << 9) + x);
        const float4 rc = *(const float4*)(plane + (y   << 9) + x);
        const float4 rd = *(const float4*)(plane + (yp1 << 9) + x);
        const int xl = (x > 0)      ? x - 1 : 0;
        const int xr = (x + 4 < W_) ? x + 4 : W_ - 1;
        const float la = plane[(ym1 << 9) + xl];
        const float lb = plane[(y   << 9) + xl];
        const float lc = plane[(yp1 << 9) + xl];
        const float ka = plane[(ym1 << 9) + xr];
        const float kb = plane[(y   << 9) + xr];
        const float kc = plane[(yp1 << 9) + xr];

        const float vm0 = max3f(ru.x, rc.x, rd.x);
        const float vm1 = max3f(ru.y, rc.y, rd.y);
        const float vm2 = max3f(ru.z, rc.z, rd.z);
        const float vm3 = max3f(ru.w, rc.w, rd.w);
        const float lv  = (x > 0)      ? max3f(la, lb, lc) : -FLT_MAX;
        const float rv  = (x + 4 < W_) ? max3f(ka, kb, kc) : -FLT_MAX;

        const float w0 = fmaxf(lv, fmaxf(vm0, vm1));
        const float w1 = max3f(vm0, vm1, vm2);
        const float w2 = max3f(vm1, vm2, vm3);
        const float w3 = fmaxf(fmaxf(vm2, vm3), rv);

        const int base = ((y << 9) + x) * C_ + cls;   // reference flat index

        const float vals[4] = { rc.x, rc.y, rc.z, rc.w };
        const float wins[4] = { w0, w1, w2, w3 };
#pragma unroll
        for (int c2 = 0; c2 < 4; ++c2) {
            const float v = vals[c2];
            if (v > TAU && v == wins[c2]) {
                const int pos = atomicAdd(&bcnt_s, 1);   // LDS atomic
                if (pos < BSLOTS)
                    bslots[pos] = make_int2(__float_as_int(v), base + c2 * C_);
            }
        }
    }

    __syncthreads();
    const int c = bcnt_s;
    if (threadIdx.x == 0)
        gbcnt[blockIdx.x] = (unsigned char)((c > 255) ? 255 : c);
    if ((int)threadIdx.x < ((c < BSLOTS) ? c : BSLOTS))
        gbpair[blockIdx.x * BSLOTS + threadIdx.x] = bslots[threadIdx.x];
}

// ---------------------------------------------------------------------------
// k_reduce: single block, latency-optimized. Counts: 20 coalesced lines with
// known addresses. Entries: <=5 independent gathers per thread, all addresses
// known after the count pass -> high MLP. Valid iff every block count <=
// BSLOTS and total >= 10 (then candidates provably contain the top-10, since
// every candidate > TAU >= any non-candidate score). Else exhaustive fallback.
// ---------------------------------------------------------------------------
__global__ __launch_bounds__(256) void k_reduce(const unsigned char* __restrict__ gbcnt,
                                                const int2* __restrict__ gbpair,
                                                const float* __restrict__ kp,
                                                const float* __restrict__ off,
                                                const float* __restrict__ sz,
                                                float* __restrict__ out)
{
    const int t = threadIdx.x;
    float tv[K_];
    int   ti[K_];
#pragma unroll
    for (int k = 0; k < K_; ++k) { tv[k] = 0.0f; ti[k] = INT_MAX; }

    // ---- phase 1: load my 5 block counts (independent loads) ---------------
    int c[BPT];
#pragma unroll
    for (int k = 0; k < BPT; ++k)
        c[k] = (int)gbcnt[t + k * 256];

    int myn = 0, myok = 1;
#pragma unroll
    for (int k = 0; k < BPT; ++k) {
        if (c[k] > BSLOTS) { myok = 0; c[k] = 0; }
        myn += c[k];
    }

    // ---- phase 2: gather candidate entries (addresses known, parallel) -----
#pragma unroll
    for (int k = 0; k < BPT; ++k) {
        const int b = t + k * 256;
        for (int j = 0; j < c[k]; ++j) {
            const int2 e = gbpair[b * BSLOTS + j];
            insert10(tv, ti, __int_as_float(e.x), e.y);
        }
    }

    // ---- validity reduction ------------------------------------------------
    __shared__ int sn[256], sk[256];
    sn[t] = myn; sk[t] = myok;
    __syncthreads();
    for (int st = 128; st > 0; st >>= 1) {
        if (t < st) { sn[t] += sn[t + st]; sk[t] &= sk[t + st]; }
        __syncthreads();
    }
    const bool valid = (sk[0] != 0) && (sn[0] >= K_);
    __syncthreads();

    if (!valid) {
        // exhaustive fallback (never taken for the benchmark input)
#pragma unroll
        for (int k = 0; k < K_; ++k) { tv[k] = 0.0f; ti[k] = INT_MAX; }
        float thresh = 0.0f;
        for (int idx = t; idx < NTOT; idx += 256) {
            const int cls = idx >> 18;
            const int sp  = idx & (HW_ - 1);
            const int y   = sp >> 9;
            const int x   = sp & (W_ - 1);
            const float* plane = kp + (cls << 18);
            const float v = plane[sp];
            float wmax = v;
            const int yA = (y > 0)      ? y - 1 : 0;
            const int yB = (y < H_ - 1) ? y + 1 : H_ - 1;
            const int xA = (x > 0)      ? x - 1 : 0;
            const int xB = (x < W_ - 1) ? x + 1 : W_ - 1;
            for (int yy = yA; yy <= yB; ++yy)
                for (int xx = xA; xx <= xB; ++xx)
                    wmax = fmaxf(wmax, plane[(yy << 9) + xx]);
            if (v == wmax && v > thresh) {
                insert10(tv, ti, v, sp * C_ + cls);
                thresh = tv[K_ - 1];
            }
        }
    }

    // ---- block merge of sorted 10-lists ------------------------------------
    __shared__ float sv[256][K_];
    __shared__ int   si[256][K_];
#pragma unroll
    for (int k = 0; k < K_; ++k) { sv[t][k] = tv[k]; si[t][k] = ti[k]; }
    __syncthreads();

    for (int stride = 128; stride > 0; stride >>= 1) {
        if (t < stride) {
            float mv[K_]; int mi[K_];
            int a = 0, b = 0;
#pragma unroll
            for (int k = 0; k < K_; ++k) {
                const float va = sv[t][a], vb = sv[t + stride][b];
                const int   ia = si[t][a], ib = si[t + stride][b];
                const bool takeA = (va > vb) || (va == vb && ia <= ib);
                if (takeA) { mv[k] = va; mi[k] = ia; ++a; }
                else       { mv[k] = vb; mi[k] = ib; ++b; }
            }
#pragma unroll
            for (int k = 0; k < K_; ++k) { sv[t][k] = mv[k]; si[t][k] = mi[k]; }
        }
        __syncthreads();
    }

    if (t < K_) {
        const float score = sv[0][t];
        const int   index = si[0][t];
        const int   chan  = index / C_;          // y*W + x
        const int   cls   = index - chan * C_;
        const int   y     = chan >> 9;
        const int   x     = chan & (W_ - 1);

        // last-dim flip: y-component <- channel 1, x-component <- channel 0
        const float offy = off[HW_ + chan];
        const float offx = off[chan];
        const float szy  = sz[HW_ + chan];
        const float szx  = sz[chan];

        const float py = (float)y + offy;
        const float px = (float)x + offx;
        const float hy = 0.5f * szy;
        const float hx = 0.5f * szx;

        const float lo = 0.0f, hi = (float)(W_ - 1);
        out[t * 4 + 0] = fminf(fmaxf(py - hy, lo), hi) * 4.0f;
        out[t * 4 + 1] = fminf(fmaxf(px - hx, lo), hi) * 4.0f;
        out[t * 4 + 2] = fminf(fmaxf(py + hy, lo), hi) * 4.0f;
        out[t * 4 + 3] = fminf(fmaxf(px + hx, lo), hi) * 4.0f;
        out[40 + t]    = (float)cls;   // detection_classes
        out[50 + t]    = score;        // detection_scores
    }
}

// ---------------------------------------------------------------------------
extern "C" void kernel_launch(void* const* d_in, const int* in_sizes, int n_in,
                              void* d_out, int out_size, void* d_ws, size_t ws_size,
                              hipStream_t stream)
{
    const float* off = (const float*)d_in[0];   // [1,2,512,512]
    const float* sz  = (const float*)d_in[1];   // [1,2,512,512]
    const float* kp  = (const float*)d_in[2];   // [1,80,512,512]
    float* out = (float*)d_out;                 // 40 + 10 + 10 = 60 floats

    // ws layout: gbcnt[NBLK] bytes (padded to 256) | gbpair[NBLK*BSLOTS] int2
    unsigned char* gbcnt = (unsigned char*)d_ws;
    int2* gbpair = (int2*)((char*)d_ws + ((NBLK + 255) & ~255));

    k_scan<<<NBLK, 256, 0, stream>>>(kp, gbcnt, gbpair);
    k_reduce<<<1, 256, 0, stream>>>(gbcnt, gbpair, kp, off, sz, out);
}

// Round 9
// 49.046 us; speedup vs baseline: 1.6852x; 1.1250x over previous
//
#include <hip/hip_runtime.h>
#include <climits>
#include <float.h>

#define H_     512
#define W_     512
#define C_     80
#define HW_    (H_ * W_)           // 262144
#define NTOT   (C_ * HW_)          // 20,971,520
#define K_     10
#define R_     16                  // rows per strip
#define NSTRIP (C_ * (H_ / R_) * (W_ / 4))   // 80*32*128 = 327680
#define NBLK   (NSTRIP / 256)                // 1280 scan blocks
#define BSLOTS 8                             // per-block candidate slots (64 B)
#define PHB    20                            // gather blocks
#define SRCPB  (NBLK / PHB)                  // 64 source blocks per gather block
#define TAU    0.9999f

__device__ __forceinline__ float max3f(float a, float b, float c) {
    return fmaxf(fmaxf(a, b), c);
}

// Fully-unrolled bubble insert into descending (tv, ti); tie -> lower index.
__device__ __forceinline__ void insert10(float (&tv)[K_], int (&ti)[K_],
                                         float s, int ridx) {
#pragma unroll
    for (int j = 0; j < K_; ++j) {
        const bool better = (s > tv[j]) || (s == tv[j] && ridx < ti[j]);
        const float ov = tv[j]; const int oi = ti[j];
        if (better) { tv[j] = s; ti[j] = ridx; s = ov; ridx = oi; }
    }
}

// Merge 256 sorted 10-lists in LDS down to one (result in sv[0]/si[0]).
__device__ __forceinline__ void block_merge(float (*sv)[K_], int (*si)[K_], int t) {
    for (int stride = 128; stride > 0; stride >>= 1) {
        if (t < stride) {
            float mv[K_]; int mi[K_];
            int a = 0, b = 0;
#pragma unroll
            for (int k = 0; k < K_; ++k) {
                const float va = sv[t][a], vb = sv[t + stride][b];
                const int   ia = si[t][a], ib = si[t + stride][b];
                const bool takeA = (va > vb) || (va == vb && ia <= ib);
                if (takeA) { mv[k] = va; mi[k] = ia; ++a; }
                else       { mv[k] = vb; mi[k] = ib; ++b; }
            }
#pragma unroll
            for (int k = 0; k < K_; ++k) { sv[t][k] = mv[k]; si[t][k] = mi[k]; }
        }
        __syncthreads();
    }
}

// ---------------------------------------------------------------------------
// k_scan: per-thread 16-row strip; hot loop = 1 float4 load + 3 fmax + 1 cmp
// + ballot per row. Rare wave-uniform 3x3 re-evaluation; candidates compacted
// via LDS into one 64 B line + one count int per block. Block 0 also zeroes
// the dispatch-2 done counter (visible to k_gather via dispatch boundary).
// ---------------------------------------------------------------------------
__global__ __launch_bounds__(256) void k_scan(const float* __restrict__ kp,
                                              int*  __restrict__ gbcnt,
                                              int2* __restrict__ gbpair,
                                              int*  __restrict__ done)
{
    __shared__ int  bcnt_s;
    __shared__ int2 bslots[BSLOTS];
    if (threadIdx.x == 0) bcnt_s = 0;
    __syncthreads();

    const int s   = blockIdx.x * 256 + threadIdx.x;   // strip id
    const int cls = s >> 12;                          // 4096 strips per plane
    const int r   = s & 4095;
    const int g   = r >> 7;                           // rowgroup (32 per plane)
    const int xc  = r & 127;                          // x-chunk
    const int y0  = g << 4;
    const int x   = xc << 2;

    const float* plane = kp + (cls << 18);
    const float* p     = plane + (y0 << 9) + x;

    // ---- hot loop ----------------------------------------------------------
    unsigned whot = 0;
#pragma unroll
    for (int i = 0; i < R_; ++i) {
        const float4 rc = *(const float4*)(p + (i << 9));
        const float m4 = fmaxf(fmaxf(rc.x, rc.y), fmaxf(rc.z, rc.w));
        const unsigned long long bl = __ballot(m4 > TAU);
        whot |= (bl != 0ull ? 1u : 0u) << i;
    }

    // ---- rare pass ---------------------------------------------------------
    while (whot) {
        const int i = __ffs(whot) - 1;
        whot &= whot - 1;

        const int y   = y0 + i;
        const int ym1 = (y > 0)      ? y - 1 : 0;
        const int yp1 = (y < H_ - 1) ? y + 1 : H_ - 1;
        const float4 ru = *(const float4*)(plane + (ym1 << 9) + x);
        const float4 rc = *(const float4*)(plane + (y   << 9) + x);
        const float4 rd = *(const float4*)(plane + (yp1 << 9) + x);
        const int xl = (x > 0)      ? x - 1 : 0;
        const int xr = (x + 4 < W_) ? x + 4 : W_ - 1;
        const float la = plane[(ym1 << 9) + xl];
        const float lb = plane[(y   << 9) + xl];
        const float lc = plane[(yp1 << 9) + xl];
        const float ka = plane[(ym1 << 9) + xr];
        const float kb = plane[(y   << 9) + xr];
        const float kc = plane[(yp1 << 9) + xr];

        const float vm0 = max3f(ru.x, rc.x, rd.x);
        const float vm1 = max3f(ru.y, rc.y, rd.y);
        const float vm2 = max3f(ru.z, rc.z, rd.z);
        const float vm3 = max3f(ru.w, rc.w, rd.w);
        const float lv  = (x > 0)      ? max3f(la, lb, lc) : -FLT_MAX;
        const float rv  = (x + 4 < W_) ? max3f(ka, kb, kc) : -FLT_MAX;

        const float w0 = fmaxf(lv, fmaxf(vm0, vm1));
        const float w1 = max3f(vm0, vm1, vm2);
        const float w2 = max3f(vm1, vm2, vm3);
        const float w3 = fmaxf(fmaxf(vm2, vm3), rv);

        const int base = ((y << 9) + x) * C_ + cls;   // reference flat index

        const float vals[4] = { rc.x, rc.y, rc.z, rc.w };
        const float wins[4] = { w0, w1, w2, w3 };
#pragma unroll
        for (int c2 = 0; c2 < 4; ++c2) {
            const float v = vals[c2];
            if (v > TAU && v == wins[c2]) {
                const int pos = atomicAdd(&bcnt_s, 1);   // LDS atomic
                if (pos < BSLOTS)
                    bslots[pos] = make_int2(__float_as_int(v), base + c2 * C_);
            }
        }
    }

    __syncthreads();
    const int c = bcnt_s;
    if (threadIdx.x == 0) gbcnt[blockIdx.x] = c;
    if ((int)threadIdx.x < ((c < BSLOTS) ? c : BSLOTS))
        gbpair[blockIdx.x * BSLOTS + threadIdx.x] = bslots[threadIdx.x];

    if (blockIdx.x == 0 && threadIdx.x == 0) *done = 0;
}

// ---------------------------------------------------------------------------
// k_gather: 20 blocks. Block b gathers SRCPB=64 source blocks: lane t<64 reads
// gbcnt + all 8 slots unconditionally (4 independent int4 loads), inserts the
// first c entries, block-merges -> sorted top-10 + (n, ok) packed to gmid.
// Last-arriving block (device-scope atomic) merges the 20 lists, validates
// (all counts <= BSLOTS and total >= 10 => candidates provably contain the
// global top-10), else exhaustive fallback; then decodes boxes.
// ---------------------------------------------------------------------------
__global__ __launch_bounds__(256) void k_gather(const int*  __restrict__ gbcnt,
                                                const int4* __restrict__ gbpair4,
                                                unsigned long long* __restrict__ gmid,
                                                int* __restrict__ done,
                                                const float* __restrict__ kp,
                                                const float* __restrict__ off,
                                                const float* __restrict__ sz,
                                                float* __restrict__ out)
{
    __shared__ float sv[256][K_];
    __shared__ int   si[256][K_];
    __shared__ int   sn[256], sk[256];
    __shared__ int   lastFlag;

    const int t = threadIdx.x;
    float tv[K_];
    int   ti[K_];
#pragma unroll
    for (int k = 0; k < K_; ++k) { tv[k] = 0.0f; ti[k] = INT_MAX; }
    int myn = 0, myok = 1;

    if (t < SRCPB) {
        const int sb = blockIdx.x * SRCPB + t;
        int c = gbcnt[sb];
        // unconditional 64 B slot read: 4 independent int4 loads
        const int4 q0 = gbpair4[sb * 4 + 0];
        const int4 q1 = gbpair4[sb * 4 + 1];
        const int4 q2 = gbpair4[sb * 4 + 2];
        const int4 q3 = gbpair4[sb * 4 + 3];
        if (c < 0 || c > BSLOTS) { myok = 0; c = 0; }
        myn = c;
        if (c > 0) insert10(tv, ti, __int_as_float(q0.x), q0.y);
        if (c > 1) insert10(tv, ti, __int_as_float(q0.z), q0.w);
        if (c > 2) insert10(tv, ti, __int_as_float(q1.x), q1.y);
        if (c > 3) insert10(tv, ti, __int_as_float(q1.z), q1.w);
        if (c > 4) insert10(tv, ti, __int_as_float(q2.x), q2.y);
        if (c > 5) insert10(tv, ti, __int_as_float(q2.z), q2.w);
        if (c > 6) insert10(tv, ti, __int_as_float(q3.x), q3.y);
        if (c > 7) insert10(tv, ti, __int_as_float(q3.z), q3.w);
    }

    sn[t] = myn; sk[t] = myok;
#pragma unroll
    for (int k = 0; k < K_; ++k) { sv[t][k] = tv[k]; si[t][k] = ti[k]; }
    __syncthreads();
    for (int st = 128; st > 0; st >>= 1) {
        if (t < st) { sn[t] += sn[t + st]; sk[t] &= sk[t + st]; }
        __syncthreads();
    }
    block_merge(sv, si, t);

    // write my sorted list + (n, ok): 11 packed u64 words
    if (t < K_)
        gmid[blockIdx.x * 11 + t] =
            ((unsigned long long)(unsigned)si[0][t] << 32) |
            (unsigned long long)(unsigned)__float_as_uint(sv[0][t]);
    if (t == 0)
        gmid[blockIdx.x * 11 + K_] =
            ((unsigned long long)(unsigned)sk[0] << 32) |
            (unsigned long long)(unsigned)sn[0];

    __threadfence();
    if (t == 0) {
        const int old = atomicAdd(done, 1);
        lastFlag = (old == PHB - 1);
    }
    __syncthreads();
    if (!lastFlag) return;
    __threadfence();   // acquire side

    // ---- final phase: merge the 20 lists ----------------------------------
#pragma unroll
    for (int k = 0; k < K_; ++k) { tv[k] = 0.0f; ti[k] = INT_MAX; }
    myn = 0; myok = 1;

    if (t < PHB * 11) {
        const unsigned long long w = __hip_atomic_load(
            &gmid[t], __ATOMIC_RELAXED, __HIP_MEMORY_SCOPE_AGENT);
        const int lo = (int)(unsigned)(w & 0xFFFFFFFFull);
        const int hi = (int)(unsigned)(w >> 32);
        if ((t % 11) == K_) { myn = lo; myok = hi; }
        else insert10(tv, ti, __int_as_float(lo), hi);
    }

    __syncthreads();   // re-use of sv/si/sn/sk after earlier phase
    sn[t] = myn; sk[t] = myok;
#pragma unroll
    for (int k = 0; k < K_; ++k) { sv[t][k] = tv[k]; si[t][k] = ti[k]; }
    __syncthreads();
    for (int st = 128; st > 0; st >>= 1) {
        if (t < st) { sn[t] += sn[t + st]; sk[t] &= sk[t + st]; }
        __syncthreads();
    }
    const bool valid = (sk[0] != 0) && (sn[0] >= K_);   // block-uniform
    __syncthreads();

    if (!valid) {
        // exhaustive fallback (never taken for the benchmark input).
        // Block-uniform branch -> __syncthreads inside is legal.
#pragma unroll
        for (int k = 0; k < K_; ++k) { tv[k] = 0.0f; ti[k] = INT_MAX; }
        float thresh = 0.0f;
        for (int idx = t; idx < NTOT; idx += 256) {
            const int cls = idx >> 18;
            const int sp  = idx & (HW_ - 1);
            const int y   = sp >> 9;
            const int x   = sp & (W_ - 1);
            const float* plane = kp + (cls << 18);
            const float v = plane[sp];
            float wmax = v;
            const int yA = (y > 0)      ? y - 1 : 0;
            const int yB = (y < H_ - 1) ? y + 1 : H_ - 1;
            const int xA = (x > 0)      ? x - 1 : 0;
            const int xB = (x < W_ - 1) ? x + 1 : W_ - 1;
            for (int yy = yA; yy <= yB; ++yy)
                for (int xx = xA; xx <= xB; ++xx)
                    wmax = fmaxf(wmax, plane[(yy << 9) + xx]);
            if (v == wmax && v > thresh) {
                insert10(tv, ti, v, sp * C_ + cls);
                thresh = tv[K_ - 1];
            }
        }
#pragma unroll
        for (int k = 0; k < K_; ++k) { sv[t][k] = tv[k]; si[t][k] = ti[k]; }
        __syncthreads();
    }

    // merge runs UNCONDITIONALLY (r8 bug: valid path skipped it)
    block_merge(sv, si, t);

    if (t < K_) {
        const float score = sv[0][t];
        const int   index = si[0][t];
        const int   chan  = index / C_;          // y*W + x
        const int   cls   = index - chan * C_;
        const int   y     = chan >> 9;
        const int   x     = chan & (W_ - 1);

        // last-dim flip: y-component <- channel 1, x-component <- channel 0
        const float offy = off[HW_ + chan];
        const float offx = off[chan];
        const float szy  = sz[HW_ + chan];
        const float szx  = sz[chan];

        const float py = (float)y + offy;
        const float px = (float)x + offx;
        const float hy = 0.5f * szy;
        const float hx = 0.5f * szx;

        const float lo = 0.0f, hi = (float)(W_ - 1);
        out[t * 4 + 0] = fminf(fmaxf(py - hy, lo), hi) * 4.0f;
        out[t * 4 + 1] = fminf(fmaxf(px - hx, lo), hi) * 4.0f;
        out[t * 4 + 2] = fminf(fmaxf(py + hy, lo), hi) * 4.0f;
        out[t * 4 + 3] = fminf(fmaxf(px + hx, lo), hi) * 4.0f;
        out[40 + t]    = (float)cls;   // detection_classes
        out[50 + t]    = score;        // detection_scores
    }
}

// ---------------------------------------------------------------------------
extern "C" void kernel_launch(void* const* d_in, const int* in_sizes, int n_in,
                              void* d_out, int out_size, void* d_ws, size_t ws_size,
                              hipStream_t stream)
{
    const float* off = (const float*)d_in[0];   // [1,2,512,512]
    const float* sz  = (const float*)d_in[1];   // [1,2,512,512]
    const float* kp  = (const float*)d_in[2];   // [1,80,512,512]
    float* outp = (float*)d_out;                // 40 + 10 + 10 = 60 floats

    // ws layout (all rewritten every call):
    //   gbcnt  int [1280]   @ 0      (5120 B)
    //   gbpair int2[1280*8] @ 8192   (81920 B)   (also read as int4*)
    //   gmid   u64 [220]    @ 98304  (1760 B)
    //   done   int          @ 102400
    char* w = (char*)d_ws;
    int*  gbcnt  = (int*) (w + 0);
    int2* gbpair = (int2*)(w + 8192);
    unsigned long long* gmid = (unsigned long long*)(w + 98304);
    int*  done   = (int*) (w + 102400);

    k_scan<<<NBLK, 256, 0, stream>>>(kp, gbcnt, gbpair, done);
    k_gather<<<PHB, 256, 0, stream>>>(gbcnt, (const int4*)gbpair, gmid, done,
                                      kp, off, sz, outp);
}